// Round 16
// baseline (727.821 us; speedup 1.0000x reference)
//
#include <hip/hip_runtime.h>
#include <hip/hip_bf16.h>

#define N_NODES 50000
#define N_EDGES 500000
#define DIM 128
// bf16 row-local intermediates: row i occupies first 256B of the 512B f32 row slot
#define RSTRIDE 256   // elements (bf16) per row slot

typedef __bf16 bf16_t;
typedef __bf16 bf16x8 __attribute__((ext_vector_type(8)));
typedef __bf16 bf16x4 __attribute__((ext_vector_type(4)));
typedef __bf16 bf16x2 __attribute__((ext_vector_type(2)));
typedef float f32x4 __attribute__((ext_vector_type(4)));

#define MFMA(a,b,c) __builtin_amdgcn_mfma_f32_16x16x32_bf16((a),(b),(c),0,0,0)

__device__ __forceinline__ int swz(int row, int kbyte){ return kbyte ^ ((row & 7) << 4); }
__device__ __forceinline__ int hswz(int row, int kbyte){ return kbyte ^ ((row & 15) << 4); }

__device__ __forceinline__ bf16x8 lds_frag(const char* s, int row, int rowb, int kbyte){
  return *(const bf16x8*)(s + row * rowb + swz(row, kbyte));
}

__device__ __forceinline__ void copy16(char* dst, const char* __restrict__ src, int bytes){
  for (int o = threadIdx.x * 16; o < bytes; o += blockDim.x * 16)
    *(f32x4*)(dst + o) = *(const f32x4*)(src + o);
}

// ---------------- weight prep: f32 [K][N] -> bf16 transposed swizzled image [n][k] ----------------
// mode 0: plain transposed image (WO_e, W2v, W2e: A-operands of transposed GEMMs)
// mode 1: permute output-col n -> ((n&7)<<4)|(n>>3)
// mode 4: per-half mode-1 for N=256 (W1): nn = (n>>7)<<7 | ((n&7)<<4) | ((n&127)>>3)
struct WPrep {
  const float* w[10];
  int Kd[10], Nd[10], off[10], cum[10], mode[10];
};

__global__ void k_wprep(WPrep d, char* img, int total){
  for (int idx = blockIdx.x * blockDim.x + threadIdx.x; idx < total; idx += gridDim.x * blockDim.x){
    int i = 0;
#pragma unroll
    for (int j = 1; j < 10; j++) if (idx >= d.cum[j]) i = j;
    int loc = idx - d.cum[i];
    int K = d.Kd[i], N = d.Nd[i];
    int n = loc / K, k = loc - n * K;
    float val = d.w[i][(size_t)k * N + n];
    int nn = n;
    if (d.mode[i] == 1) nn = ((n & 7) << 4) | (n >> 3);
    if (d.mode[i] == 4){ int w7 = n & 127; nn = ((n >> 7) << 7) | ((w7 & 7) << 4) | (w7 >> 3); }
    *(bf16_t*)(img + d.off[i] + nn * (K * 2) + swz(nn, k * 2)) = (bf16_t)val;
  }
}

// ---------------- CSR build ----------------
__global__ void k_count(const int* __restrict__ dst, int* __restrict__ cnt){
  int i = blockIdx.x * blockDim.x + threadIdx.x;
  if (i < N_EDGES) atomicAdd(&cnt[dst[i]], 1);
}

__global__ __launch_bounds__(1024) void k_scan(const int* __restrict__ cnt,
                                               int* __restrict__ rowptr, int* __restrict__ wp){
  __shared__ int wsum[16];
  __shared__ int wpre[16];
  __shared__ int scarry;
  const int tid = threadIdx.x, lane = tid & 63, wv = tid >> 6;
  if (tid == 0) scarry = 0;
  for (int base = 0; base < N_NODES; base += 8192){
    int i0 = base + tid * 8;
    int v[8], p[8];
    int tsum = 0;
#pragma unroll
    for (int j = 0; j < 8; j++){
      int idx = i0 + j;
      v[j] = (idx < N_NODES) ? cnt[idx] : 0;
      p[j] = tsum; tsum += v[j];
    }
    int x = tsum;
#pragma unroll
    for (int off = 1; off < 64; off <<= 1){
      int t = __shfl_up(x, off);
      if (lane >= off) x += t;
    }
    if (lane == 63) wsum[wv] = x;
    __syncthreads();
    if (tid == 0){
      int run = scarry;
#pragma unroll
      for (int j = 0; j < 16; j++){ int t = wsum[j]; wpre[j] = run; run += t; }
      scarry = run;
    }
    __syncthreads();
    int texcl = wpre[wv] + x - tsum;
#pragma unroll
    for (int j = 0; j < 8; j++){
      int idx = i0 + j;
      if (idx < N_NODES){ rowptr[idx] = texcl + p[j]; wp[idx] = texcl + p[j]; }
    }
    __syncthreads();
  }
  if (tid == 0) rowptr[N_NODES] = scarry;
}

__global__ void k_fill(const int* __restrict__ dst, int* __restrict__ wp, int* __restrict__ csr){
  int i = blockIdx.x * blockDim.x + threadIdx.x;
  if (i < N_EDGES){
    int p = atomicAdd(&wp[dst[i]], 1);
    csr[p] = i;
  }
}

// ---------------- QKV: [M,128] @ 3x [128,128] -> bf16 outputs (mode-1 weights) ----------------
__global__ __launch_bounds__(512) void k_qkv(
    const float* __restrict__ v, const char* __restrict__ img,
    bf16_t* __restrict__ Q, bf16_t* __restrict__ K, bf16_t* __restrict__ V, int M)
{
  __shared__ __align__(16) char sm[65536];
  char* sX = sm;
  char* sW = sm + 32768;
  const int tid = threadIdx.x, lane = tid & 63, wave = tid >> 6;
  const int r0 = blockIdx.x * 128;
  for (int c = tid; c < 2048; c += 512){
    int row = c >> 4, kc = c & 15, grow = r0 + row;
    float f[8];
    if (grow < M){
      const float4* p = (const float4*)(v + (size_t)grow * DIM + kc * 8);
      float4 u0 = p[0], u1 = p[1];
      f[0]=u0.x; f[1]=u0.y; f[2]=u0.z; f[3]=u0.w;
      f[4]=u1.x; f[5]=u1.y; f[6]=u1.z; f[7]=u1.w;
    } else {
#pragma unroll
      for (int j=0;j<8;j++) f[j] = 0.f;
    }
    bf16x8 o;
#pragma unroll
    for (int j=0;j<8;j++) o[j] = (bf16_t)f[j];
    *(bf16x8*)(sX + row * 256 + swz(row, kc * 16)) = o;
  }
  const int rowA = wave * 16 + (lane & 15);
  const int kb0 = (lane >> 4) * 16;
  const int crow = wave*16 + (lane >> 4)*4;
  const int ccol = lane & 15;
  const f32x4 zero4 = {0.f, 0.f, 0.f, 0.f};
#pragma unroll
  for (int w3 = 0; w3 < 3; w3++){
    __syncthreads();
    copy16(sW, img + w3 * 32768, 32768);
    __syncthreads();
    f32x4 acc[8];
#pragma unroll
    for (int b=0;b<8;b++) acc[b] = zero4;
#pragma unroll
    for (int ks=0; ks<4; ks++){
      bf16x8 a = lds_frag(sX, rowA, 256, ks*64 + kb0);
#pragma unroll
      for (int nt=0; nt<8; nt++){
        int rn = nt*16 + (lane & 15);
        bf16x8 b = lds_frag(sW, rn, 256, ks*64 + kb0);
        acc[nt] = MFMA(a, b, acc[nt]);
      }
    }
    bf16_t* o = (w3 == 0) ? Q : ((w3 == 1) ? K : V);
#pragma unroll
    for (int r=0; r<4; r++){
      int grow = r0 + crow + r;
      if (grow < M){
        bf16x8 t;
#pragma unroll
        for (int nt=0; nt<8; nt++) t[nt] = (bf16_t)acc[nt][r];
        *(bf16x8*)(o + (size_t)grow * DIM + ccol*8) = t;
      }
    }
  }
}

// ---------------- fused edge attention: 2-tile software pipeline ----------------
// Per block: tiles A (r0A) and B (r0A+128). Tile B's e-loads fly during tile A's
// GEMM2+epilogue; W2^T frags loaded once; We re-staged L2-hot; stats reduced once.
__global__ __launch_bounds__(512, 4) void k_edge(
    const float* __restrict__ e,
    const int* __restrict__ src, const int* __restrict__ dst,
    const bf16_t* __restrict__ Qb, const bf16_t* __restrict__ Kb,
    const char* __restrict__ imgWe, const char* __restrict__ imgWo,
    const float* __restrict__ bOe,
    bf16_t* __restrict__ e1_pre, float* __restrict__ sv,
    float* __restrict__ stats, int M)
{
  __shared__ __align__(16) char sm[66560];
  char* sBuf = sm;                        // We -> scoreA -> We -> scoreB
  char* sE   = sm + 32768;                // bf16 e tile (residual source), A then B
  float* sStats = (float*)(sm + 65536);
  const int tid = threadIdx.x, lane = tid & 63, wave = tid >> 6;
  const int r0A = blockIdx.x * 256;
  const int r0B = r0A + 128;
  const int q = lane >> 4, ccol = lane & 15;
  const int crow = wave*16 + q*4;
  const int rowA = wave*16 + ccol;
  const int kb0 = q * 16;
  const f32x4 zero4 = {0.f,0.f,0.f,0.f};
  const float4 bo = *(const float4*)(bOe + crow);
  float s1[4] = {0.f,0.f,0.f,0.f}, s2[4] = {0.f,0.f,0.f,0.f};

  // ---- tile A loads ----
  bf16x8 Kg[4], Qg[4];
#pragma unroll
  for (int r=0;r<4;r++){
    int ed = r0A + crow + r; if (ed >= M) ed = M - 1;
    int sn = src[ed], dn = dst[ed];
    Kg[r] = *(const bf16x8*)(Kb + (size_t)sn * DIM + ccol * 8);
    Qg[r] = *(const bf16x8*)(Qb + (size_t)dn * DIM + ccol * 8);
  }
  int grA = r0A + rowA; if (grA >= M) grA = M - 1;
  {
    const f32x4* epA = (const f32x4*)(e + (size_t)grA * DIM);
    f32x4 ea[8];
#pragma unroll
    for (int ks=0; ks<4; ks++){
      ea[2*ks]   = epA[ks*8 + q*2];
      ea[2*ks+1] = epA[ks*8 + q*2 + 1];
    }
    copy16(sBuf, imgWe, 32768);
    bf16x8 eAb[4];
#pragma unroll
    for (int ks=0; ks<4; ks++){
#pragma unroll
      for (int j=0;j<4;j++){
        eAb[ks][j]   = (bf16_t)ea[2*ks][j];
        eAb[ks][4+j] = (bf16_t)ea[2*ks+1][j];
      }
    }
#pragma unroll
    for (int ks=0; ks<4; ks++)
      *(bf16x8*)(sE + rowA*256 + swz(rowA, ks*64 + kb0)) = eAb[ks];
    __syncthreads();   // B1: We + sE(A) staged
    // GEMM1(A)
    f32x4 pe[8];
#pragma unroll
    for (int i=0;i<8;i++) pe[i] = zero4;
#pragma unroll
    for (int ks=0; ks<4; ks++){
#pragma unroll
      for (int nt=0; nt<8; nt++){
        bf16x8 b = lds_frag(sBuf, nt*16 + ccol, 256, ks*64 + kb0);
        pe[nt] = MFMA(eAb[ks], b, pe[nt]);
      }
    }
    __syncthreads();   // B2: done reading We
    // score(A)
#pragma unroll
    for (int r=0;r<4;r++){
      int row = crow + r;
      bf16x8 t;
      float hsum = 0.f;
#pragma unroll
      for (int nt=0; nt<8; nt++){
        float sc = pe[nt][r] * 0.25f * (float)Kg[r][nt] * (float)Qg[r][nt];
        t[nt] = (bf16_t)sc;
        hsum += sc;
      }
      *(bf16x8*)(sBuf + row*256 + swz(row, ccol*16)) = t;
      float ts = hsum + __shfl_xor(hsum, 1);
      int ed = r0A + row;
      if (!(ccol & 1) && ed < M)
        sv[(size_t)ed*8 + (ccol >> 1)] = __expf(fminf(5.f, fmaxf(-5.f, ts)));
    }
  }
  // issue tile B e-loads (fly during GEMM2(A) + epilogue(A))
  int grB = r0B + rowA; if (grB >= M) grB = M - 1;
  f32x4 eaB[8];
  {
    const f32x4* epB = (const f32x4*)(e + (size_t)grB * DIM);
#pragma unroll
    for (int ks=0; ks<4; ks++){
      eaB[2*ks]   = epB[ks*8 + q*2];
      eaB[2*ks+1] = epB[ks*8 + q*2 + 1];
    }
  }
  // W2^T frags (reused for both tiles)
  bf16x8 w2a[4];
#pragma unroll
  for (int ks=0; ks<4; ks++)
    w2a[ks] = *(const bf16x8*)(imgWo + rowA*256 + swz(rowA, ks*64 + kb0));
  __syncthreads();   // B3: score(A) staged
  {
    f32x4 a2[8];
#pragma unroll
    for (int i=0;i<8;i++) a2[i] = zero4;
#pragma unroll
    for (int ks=0; ks<4; ks++){
#pragma unroll
      for (int nt=0; nt<8; nt++){
        bf16x8 b = lds_frag(sBuf, nt*16 + ccol, 256, ks*64 + kb0);
        a2[nt] = MFMA(w2a[ks], b, a2[nt]);
      }
    }
    // epilogue(A)
#pragma unroll
    for (int nt=0; nt<8; nt++){
      int m = nt*16 + ccol;
      int erow = r0A + m;
      bf16x4 u = *(const bf16x4*)(sE + m*256 + swz(m, crow*2));
      float val[4];
      val[0] = a2[nt][0] + (float)u[0] + bo.x;
      val[1] = a2[nt][1] + (float)u[1] + bo.y;
      val[2] = a2[nt][2] + (float)u[2] + bo.z;
      val[3] = a2[nt][3] + (float)u[3] + bo.w;
      if (erow < M){
        bf16x4 t;
#pragma unroll
        for (int r=0;r<4;r++) t[r] = (bf16_t)val[r];
        *(bf16x4*)(e1_pre + (size_t)erow*RSTRIDE + crow) = t;
      } else {
#pragma unroll
        for (int r=0;r<4;r++) val[r] = 0.f;
      }
#pragma unroll
      for (int r=0;r<4;r++){ s1[r] += val[r]; s2[r] += val[r]*val[r]; }
    }
  }
  __syncthreads();   // B4: done with sE(A), sBuf(scoreA)

  // ---- tile B setup ----
#pragma unroll
  for (int r=0;r<4;r++){
    int ed = r0B + crow + r; if (ed >= M) ed = M - 1;
    int sn = src[ed], dn = dst[ed];
    Kg[r] = *(const bf16x8*)(Kb + (size_t)sn * DIM + ccol * 8);
    Qg[r] = *(const bf16x8*)(Qb + (size_t)dn * DIM + ccol * 8);
  }
  copy16(sBuf, imgWe, 32768);   // L2-hot re-stage
  {
    bf16x8 eAb[4];
#pragma unroll
    for (int ks=0; ks<4; ks++){
#pragma unroll
      for (int j=0;j<4;j++){
        eAb[ks][j]   = (bf16_t)eaB[2*ks][j];
        eAb[ks][4+j] = (bf16_t)eaB[2*ks+1][j];
      }
    }
#pragma unroll
    for (int ks=0; ks<4; ks++)
      *(bf16x8*)(sE + rowA*256 + swz(rowA, ks*64 + kb0)) = eAb[ks];
    __syncthreads();   // B5: We + sE(B) staged
    // GEMM1(B)
    f32x4 pe[8];
#pragma unroll
    for (int i=0;i<8;i++) pe[i] = zero4;
#pragma unroll
    for (int ks=0; ks<4; ks++){
#pragma unroll
      for (int nt=0; nt<8; nt++){
        bf16x8 b = lds_frag(sBuf, nt*16 + ccol, 256, ks*64 + kb0);
        pe[nt] = MFMA(eAb[ks], b, pe[nt]);
      }
    }
    __syncthreads();   // B6: done reading We
    // score(B)
#pragma unroll
    for (int r=0;r<4;r++){
      int row = crow + r;
      bf16x8 t;
      float hsum = 0.f;
#pragma unroll
      for (int nt=0; nt<8; nt++){
        float sc = pe[nt][r] * 0.25f * (float)Kg[r][nt] * (float)Qg[r][nt];
        t[nt] = (bf16_t)sc;
        hsum += sc;
      }
      *(bf16x8*)(sBuf + row*256 + swz(row, ccol*16)) = t;
      float ts = hsum + __shfl_xor(hsum, 1);
      int ed = r0B + row;
      if (!(ccol & 1) && ed < M)
        sv[(size_t)ed*8 + (ccol >> 1)] = __expf(fminf(5.f, fmaxf(-5.f, ts)));
    }
  }
  __syncthreads();   // B7: score(B) staged
  {
    f32x4 a2[8];
#pragma unroll
    for (int i=0;i<8;i++) a2[i] = zero4;
#pragma unroll
    for (int ks=0; ks<4; ks++){
#pragma unroll
      for (int nt=0; nt<8; nt++){
        bf16x8 b = lds_frag(sBuf, nt*16 + ccol, 256, ks*64 + kb0);
        a2[nt] = MFMA(w2a[ks], b, a2[nt]);
      }
    }
    // epilogue(B)
#pragma unroll
    for (int nt=0; nt<8; nt++){
      int m = nt*16 + ccol;
      int erow = r0B + m;
      bf16x4 u = *(const bf16x4*)(sE + m*256 + swz(m, crow*2));
      float val[4];
      val[0] = a2[nt][0] + (float)u[0] + bo.x;
      val[1] = a2[nt][1] + (float)u[1] + bo.y;
      val[2] = a2[nt][2] + (float)u[2] + bo.z;
      val[3] = a2[nt][3] + (float)u[3] + bo.w;
      if (erow < M){
        bf16x4 t;
#pragma unroll
        for (int r=0;r<4;r++) t[r] = (bf16_t)val[r];
        *(bf16x4*)(e1_pre + (size_t)erow*RSTRIDE + crow) = t;
      } else {
#pragma unroll
        for (int r=0;r<4;r++) val[r] = 0.f;
      }
#pragma unroll
      for (int r=0;r<4;r++){ s1[r] += val[r]; s2[r] += val[r]*val[r]; }
    }
  }
  // stats reduce (both tiles)
#pragma unroll
  for (int r=0;r<4;r++){
    s1[r] += __shfl_xor(s1[r], 1); s1[r] += __shfl_xor(s1[r], 2);
    s1[r] += __shfl_xor(s1[r], 4); s1[r] += __shfl_xor(s1[r], 8);
    s2[r] += __shfl_xor(s2[r], 1); s2[r] += __shfl_xor(s2[r], 2);
    s2[r] += __shfl_xor(s2[r], 4); s2[r] += __shfl_xor(s2[r], 8);
  }
  if (ccol == 0){
#pragma unroll
    for (int r=0;r<4;r++){
      sStats[crow + r] = s1[r];
      sStats[128 + crow + r] = s2[r];
    }
  }
  __syncthreads();
  if (tid < 256) unsafeAtomicAdd(&stats[tid], sStats[tid]);
}

// ---------------- aggregation: one wave per node, CSR walk, 4-deep pipelined ----------------
__global__ __launch_bounds__(512) void k_agg(
    const int* __restrict__ rowptr, const int* __restrict__ csr,
    const int* __restrict__ src, const float* __restrict__ envl,
    const float* __restrict__ sv, const bf16_t* __restrict__ V,
    bf16_t* __restrict__ vAttn, int M)
{
  const int wave = threadIdx.x >> 6, lane = threadIdx.x & 63;
  const int n = blockIdx.x * 8 + wave;
  if (n >= M) return;
  const int beg = rowptr[n], end = rowptr[n + 1];
  const int h = lane >> 3;
  float ax = 0.f, ay = 0.f, zacc = 0.f;
  int i = beg;
  for (; i + 4 <= end; i += 4){
    int e0 = csr[i], e1 = csr[i+1], e2 = csr[i+2], e3 = csr[i+3];
    int sn0 = src[e0], sn1 = src[e1], sn2 = src[e2], sn3 = src[e3];
    float sv0 = sv[(size_t)e0*8 + h], sv1 = sv[(size_t)e1*8 + h];
    float sv2 = sv[(size_t)e2*8 + h], sv3 = sv[(size_t)e3*8 + h];
    float n0 = envl[e0], n1 = envl[e1], n2 = envl[e2], n3 = envl[e3];
    bf16x2 a0 = *(const bf16x2*)(V + (size_t)sn0 * DIM + lane * 2);
    bf16x2 a1 = *(const bf16x2*)(V + (size_t)sn1 * DIM + lane * 2);
    bf16x2 a2v = *(const bf16x2*)(V + (size_t)sn2 * DIM + lane * 2);
    bf16x2 a3 = *(const bf16x2*)(V + (size_t)sn3 * DIM + lane * 2);
    float w0 = n0*sv0, w1 = n1*sv1, w2 = n2*sv2, w3 = n3*sv3;
    ax += (float)a0[0]*w0 + (float)a1[0]*w1 + (float)a2v[0]*w2 + (float)a3[0]*w3;
    ay += (float)a0[1]*w0 + (float)a1[1]*w1 + (float)a2v[1]*w2 + (float)a3[1]*w3;
    zacc += sv0 + sv1 + sv2 + sv3;
  }
  for (; i < end; i++){
    int eid = csr[i];
    int sn = src[eid];
    float s = sv[(size_t)eid * 8 + h];
    float env = envl[eid];
    const bf16x2 vv = *(const bf16x2*)(V + (size_t)sn * DIM + lane * 2);
    float w = env * s;
    ax += (float)vv[0] * w; ay += (float)vv[1] * w;
    zacc += s;
  }
  float inv = 1.f / (zacc + 1e-6f);
  bf16x2 o; o[0] = (bf16_t)(ax * inv); o[1] = (bf16_t)(ay * inv);
  *(bf16x2*)(vAttn + (size_t)n * DIM + lane * 2) = o;
}

// ---------------- node out-proj (bf16 row-local write; stats) ----------------
__global__ __launch_bounds__(512) void k_nodeout(
    const bf16_t* __restrict__ vAttn, const float* __restrict__ v,
    const char* __restrict__ imgWo, const float* __restrict__ bOv,
    bf16_t* __restrict__ v1_pre, float* __restrict__ stats, int M)
{
  __shared__ __align__(16) char sm[66560];
  char* sW = sm;
  char* sX = sm + 32768;
  float* sStats = (float*)(sm + 65536);
  const int tid = threadIdx.x, lane = tid & 63, wave = tid >> 6;
  const int r0 = blockIdx.x * 128;
  copy16(sW, imgWo, 32768);
  if (tid < 256) sStats[tid] = 0.f;
  for (int c = tid; c < 2048; c += 512){
    int row = c >> 4, kc = c & 15, grow = r0 + row;
    bf16x8 o;
    if (grow < M){
      o = *(const bf16x8*)(vAttn + (size_t)grow * DIM + kc * 8);
    } else {
#pragma unroll
      for (int j=0;j<8;j++) o[j] = (bf16_t)0.f;
    }
    *(bf16x8*)(sX + row*256 + swz(row, kc*16)) = o;
  }
  __syncthreads();
  const int rowA = wave*16 + (lane & 15);
  const int kb0 = (lane >> 4)*16;
  const f32x4 zero4 = {0.f,0.f,0.f,0.f};
  f32x4 acc[8];
#pragma unroll
  for (int i=0;i<8;i++) acc[i]=zero4;
#pragma unroll
  for (int ks=0;ks<4;ks++){
    bf16x8 a = lds_frag(sX, rowA, 256, ks*64+kb0);
#pragma unroll
    for (int nt=0;nt<8;nt++){
      int rn = nt*16 + (lane&15);
      bf16x8 b = lds_frag(sW, rn, 256, ks*64+kb0);
      acc[nt] = MFMA(a,b,acc[nt]);
    }
  }
  const int crow = wave*16 + (lane>>4)*4;
  const int ccol = lane & 15;
  float4 bo0 = *(const float4*)(bOv + ccol*8);
  float4 bo1 = *(const float4*)(bOv + ccol*8 + 4);
  float s1[8], s2[8];
#pragma unroll
  for (int j=0;j<8;j++){ s1[j]=0.f; s2[j]=0.f; }
#pragma unroll
  for (int r=0;r<4;r++){
    int grow = r0 + crow + r;
    float val[8];
    if (grow < M){
      const float4* vp = (const float4*)(v + (size_t)grow*DIM + ccol*8);
      float4 v0 = vp[0], v1 = vp[1];
      val[0]=acc[0][r]+v0.x+bo0.x; val[1]=acc[1][r]+v0.y+bo0.y;
      val[2]=acc[2][r]+v0.z+bo0.z; val[3]=acc[3][r]+v0.w+bo0.w;
      val[4]=acc[4][r]+v1.x+bo1.x; val[5]=acc[5][r]+v1.y+bo1.y;
      val[6]=acc[6][r]+v1.z+bo1.z; val[7]=acc[7][r]+v1.w+bo1.w;
      bf16x8 t;
#pragma unroll
      for (int j=0;j<8;j++) t[j] = (bf16_t)val[j];
      *(bf16x8*)(v1_pre + (size_t)grow*RSTRIDE + ccol*8) = t;
    } else {
#pragma unroll
      for (int j=0;j<8;j++) val[j]=0.f;
    }
#pragma unroll
    for (int j=0;j<8;j++){ s1[j] += val[j]; s2[j] += val[j]*val[j]; }
  }
#pragma unroll
  for (int j=0;j<8;j++){
    s1[j] += __shfl_xor(s1[j], 16); s1[j] += __shfl_xor(s1[j], 32);
    s2[j] += __shfl_xor(s2[j], 16); s2[j] += __shfl_xor(s2[j], 32);
  }
  if (lane < 16){
#pragma unroll
    for (int j=0;j<8;j++){
      atomicAdd(&sStats[ccol*8 + j], s1[j]);
      atomicAdd(&sStats[128 + ccol*8 + j], s2[j]);
    }
  }
  __syncthreads();
  if (tid < 256) unsafeAtomicAdd(&stats[tid], sStats[tid]);
}

// ---------------- stats -> scale/shift (BN1) ----------------
struct FinArgs { const float* st; const float* g; const float* b; float* ss; float invM; };

__global__ void k_finstats(FinArgs a0, FinArgs a1){
  FinArgs a = (blockIdx.x == 0) ? a0 : a1;
  int c = threadIdx.x;
  float mean = a.st[c] * a.invM;
  float var  = a.st[128 + c] * a.invM - mean * mean;
  float scl  = a.g[c] * rsqrtf(var + 1e-5f);
  a.ss[c] = scl;
  a.ss[128 + c] = a.b[c] - mean * scl;
}

// ---------------- fused FFN: dual buffer, transposed GEMM2', 6 barriers, (512,4) no-spill ----------------
__global__ __launch_bounds__(512, 4) void k_ffn(
    bf16_t* __restrict__ xio, const float* __restrict__ ss1,
    const char* __restrict__ img1, const float* __restrict__ b1,
    const char* __restrict__ img2, const float* __restrict__ b2,
    float* __restrict__ stats2, int M)
{
  __shared__ __align__(16) char sm[66560];
  char* sA = sm;            // h k-half (hswz layout)
  char* sB = sm + 32768;    // W1h0 -> W1h1 -> o2^T
  float* sStats = (float*)(sm + 65536);
  const int tid = threadIdx.x, lane = tid & 63, wave = tid >> 6;
  const int r0 = blockIdx.x * 128;
  const int q = lane >> 4, ccol = lane & 15;
  const int kb0 = q * 16;
  const int crow = wave*16 + q*4;
  const int rowA = wave*16 + ccol;
  const f32x4 zero4 = {0.f,0.f,0.f,0.f};

  // phase A: W1 half0 -> sB; x row frags + inline BN
  copy16(sB, img1, 32768);
  if (tid < 256) sStats[tid] = 0.f;
  int grA = r0 + rowA; if (grA >= M) grA = M - 1;
  const bf16_t* xrow = xio + (size_t)grA * RSTRIDE;
  bf16x8 araw[4];
#pragma unroll
  for (int ks=0; ks<4; ks++)
    araw[ks] = *(const bf16x8*)(xrow + ks*32 + q*8);
  bf16x8 xAb[4];
#pragma unroll
  for (int ks=0; ks<4; ks++){
    const f32x4* sp = (const f32x4*)(ss1 + ks*32 + q*8);
    const f32x4* hp = (const f32x4*)(ss1 + 128 + ks*32 + q*8);
    f32x4 s0 = sp[0], s1v = sp[1], h0 = hp[0], h1 = hp[1];
#pragma unroll
    for (int j=0;j<4;j++){
      xAb[ks][j]   = (bf16_t)((float)araw[ks][j]  *s0[j]  + h0[j]);
      xAb[ks][4+j] = (bf16_t)((float)araw[ks][4+j]*s1v[j] + h1[j]);
    }
  }
  __syncthreads();  // B1: W1h0 ready

  bf16x8 hreg0[4], hreg1[4];
  f32x4 wbuf[4];
#pragma unroll
  for (int i=0;i<4;i++) wbuf[i] = *(const f32x4*)(img1 + 32768 + tid*16 + i*8192);
  // GEMM1a: hcols ccol*8+nt (k-half0)
  {
    float4 bq0 = *(const float4*)(b1 + ccol*8);
    float4 bq1 = *(const float4*)(b1 + ccol*8 + 4);
    f32x4 acc[8];
#pragma unroll
    for (int i=0;i<8;i++) acc[i]=zero4;
#pragma unroll
    for (int ks=0;ks<4;ks++){
#pragma unroll
      for (int nt=0;nt<8;nt++){
        bf16x8 b = lds_frag(sB, nt*16 + ccol, 256, ks*64+kb0);
        acc[nt] = MFMA(xAb[ks], b, acc[nt]);
      }
    }
#pragma unroll
    for (int r=0;r<4;r++){
      bf16x8 t;
      t[0]=(bf16_t)fmaxf(acc[0][r]+bq0.x,0.f); t[1]=(bf16_t)fmaxf(acc[1][r]+bq0.y,0.f);
      t[2]=(bf16_t)fmaxf(acc[2][r]+bq0.z,0.f); t[3]=(bf16_t)fmaxf(acc[3][r]+bq0.w,0.f);
      t[4]=(bf16_t)fmaxf(acc[4][r]+bq1.x,0.f); t[5]=(bf16_t)fmaxf(acc[5][r]+bq1.y,0.f);
      t[6]=(bf16_t)fmaxf(acc[6][r]+bq1.z,0.f); t[7]=(bf16_t)fmaxf(acc[7][r]+bq1.w,0.f);
      hreg0[r] = t;
    }
  }
  __syncthreads();  // B2: done reading sB (W1h0)
  // write W1h1 -> sB and h0 -> sA
#pragma unroll
  for (int i=0;i<4;i++) *(f32x4*)(sB + tid*16 + i*8192) = wbuf[i];
#pragma unroll
  for (int r=0;r<4;r++){
    int row = crow + r;
    *(bf16x8*)(sA + row*256 + hswz(row, ccol*16)) = hreg0[r];
  }
  __syncthreads();  // B3: W1h1 + h0 ready (hreg0 dead)

  f32x4 o2[8];
#pragma unroll
  for (int i=0;i<8;i++) o2[i]=zero4;
  // GEMM1b: hcols 128+ccol*8+nt (reads sB)
  {
    float4 bq2 = *(const float4*)(b1 + 128 + ccol*8);
    float4 bq3 = *(const float4*)(b1 + 128 + ccol*8 + 4);
    f32x4 acc[8];
#pragma unroll
    for (int i=0;i<8;i++) acc[i]=zero4;
#pragma unroll
    for (int ks=0;ks<4;ks++){
#pragma unroll
      for (int nt=0;nt<8;nt++){
        bf16x8 b = lds_frag(sB, nt*16 + ccol, 256, ks*64+kb0);
        acc[nt] = MFMA(xAb[ks], b, acc[nt]);
      }
    }
#pragma unroll
    for (int r=0;r<4;r++){
      bf16x8 t;
      t[0]=(bf16_t)fmaxf(acc[0][r]+bq2.x,0.f); t[1]=(bf16_t)fmaxf(acc[1][r]+bq2.y,0.f);
      t[2]=(bf16_t)fmaxf(acc[2][r]+bq2.z,0.f); t[3]=(bf16_t)fmaxf(acc[3][r]+bq2.w,0.f);
      t[4]=(bf16_t)fmaxf(acc[4][r]+bq3.x,0.f); t[5]=(bf16_t)fmaxf(acc[5][r]+bq3.y,0.f);
      t[6]=(bf16_t)fmaxf(acc[6][r]+bq3.z,0.f); t[7]=(bf16_t)fmaxf(acc[7][r]+bq3.w,0.f);
      hreg1[r] = t;
    }
  }
  // GEMM2'a over k-half0 (reads sA; no barrier needed — read-read with GEMM1b)
  {
    bf16x8 w2a[4];
#pragma unroll
    for (int ks=0; ks<4; ks++)
      w2a[ks] = *(const bf16x8*)(img2 + (size_t)rowA*512 + swz(rowA, ks*64 + kb0));
#pragma unroll
    for (int ks=0; ks<4; ks++){
#pragma unroll
      for (int nt=0; nt<8; nt++){
        int m = nt*16 + ccol;
        bf16x8 b = *(const bf16x8*)(sA + m*256 + hswz(m, ks*64 + kb0));
        o2[nt] = MFMA(w2a[ks], b, o2[nt]);
      }
    }
  }
  __syncthreads();  // B4: done reading sA (h0) and sB (W1h1)
#pragma unroll
  for (int r=0;r<4;r++){
    int row = crow + r;
    *(bf16x8*)(sA + row*256 + hswz(row, ccol*16)) = hreg1[r];
  }
  __syncthreads();  // B5: h1 ready (hreg1 dead)
  // GEMM2'b over k-half1
  {
    bf16x8 w2a[4];
#pragma unroll
    for (int ks=0; ks<4; ks++)
      w2a[ks] = *(const bf16x8*)(img2 + (size_t)rowA*512 + swz(rowA, 256 + ks*64 + kb0));
#pragma unroll
    for (int ks=0; ks<4; ks++){
#pragma unroll
      for (int nt=0; nt<8; nt++){
        int m = nt*16 + ccol;
        bf16x8 b = *(const bf16x8*)(sA + m*256 + hswz(m, ks*64 + kb0));
        o2[nt] = MFMA(w2a[ks], b, o2[nt]);
      }
    }
  }
  // o2 -> bf16, transposed into sB (free since B4): row m = nt*16+ccol, cols crow..+3
#pragma unroll
  for (int nt=0; nt<8; nt++){
    int m = nt*16 + ccol;
    bf16x4 t;
#pragma unroll
    for (int r=0;r<4;r++) t[r] = (bf16_t)o2[nt][r];
    *(bf16x4*)(sB + m*256 + swz(m, crow*2)) = t;
  }
  __syncthreads();  // B6: o2^T staged

  // row-major epilogue: rows crow..+3, cols ccol*8..+7
  float4 sc0 = *(const float4*)(ss1 + ccol*8);
  float4 sc1 = *(const float4*)(ss1 + ccol*8 + 4);
  float4 sh0 = *(const float4*)(ss1 + 128 + ccol*8);
  float4 sh1 = *(const float4*)(ss1 + 128 + ccol*8 + 4);
  float4 b20 = *(const float4*)(b2 + ccol*8);
  float4 b21 = *(const float4*)(b2 + ccol*8 + 4);
  float s1[8], s2[8];
#pragma unroll
  for (int j=0;j<8;j++){ s1[j]=0.f; s2[j]=0.f; }
#pragma unroll
  for (int r=0;r<4;r++){
    int row = crow + r, grow = r0 + row;
    float val[8];
    if (grow < M){
      bf16x8 u = *(const bf16x8*)(xio + (size_t)grow*RSTRIDE + ccol*8);
      bf16x8 ob = *(const bf16x8*)(sB + row*256 + swz(row, ccol*16));
      val[0]=(float)u[0]*sc0.x+sh0.x + (float)ob[0]+b20.x;
      val[1]=(float)u[1]*sc0.y+sh0.y + (float)ob[1]+b20.y;
      val[2]=(float)u[2]*sc0.z+sh0.z + (float)ob[2]+b20.z;
      val[3]=(float)u[3]*sc0.w+sh0.w + (float)ob[3]+b20.w;
      val[4]=(float)u[4]*sc1.x+sh1.x + (float)ob[4]+b21.x;
      val[5]=(float)u[5]*sc1.y+sh1.y + (float)ob[5]+b21.y;
      val[6]=(float)u[6]*sc1.z+sh1.z + (float)ob[6]+b21.z;
      val[7]=(float)u[7]*sc1.w+sh1.w + (float)ob[7]+b21.w;
      bf16x8 t;
#pragma unroll
      for (int j=0;j<8;j++) t[j] = (bf16_t)val[j];
      *(bf16x8*)(xio + (size_t)grow*RSTRIDE + ccol*8) = t;
    } else {
#pragma unroll
      for (int j=0;j<8;j++) val[j]=0.f;
    }
#pragma unroll
    for (int j=0;j<8;j++){ s1[j] += val[j]; s2[j] += val[j]*val[j]; }
  }
#pragma unroll
  for (int j=0;j<8;j++){
    s1[j] += __shfl_xor(s1[j], 16); s1[j] += __shfl_xor(s1[j], 32);
    s2[j] += __shfl_xor(s2[j], 16); s2[j] += __shfl_xor(s2[j], 32);
  }
  if (lane < 16){
#pragma unroll
    for (int j=0;j<8;j++){
      atomicAdd(&sStats[ccol*8 + j], s1[j]);
      atomicAdd(&sStats[128 + ccol*8 + j], s2[j]);
    }
  }
  __syncthreads();  // B7
  if (tid < 256) unsafeAtomicAdd(&stats2[tid], sStats[tid]);
}

// ---------------- in-place bf16->f32 normalize-expand (in-block BN2 finalize) ----------------
struct NormP { const float* st; const float* g; const float* bn; float invM; };

__global__ __launch_bounds__(256) void k_norm2(
    char* __restrict__ xv, char* __restrict__ xe,
    NormP pv, NormP pe, long long nv, long long ne)
{
  __shared__ float sSS[512];
  const int tid = threadIdx.x;
  {
    int side = tid >> 7, c = tid & 127;
    NormP pp = side ? pe : pv;
    float mean = pp.st[c] * pp.invM;
    float var  = pp.st[128 + c] * pp.invM - mean * mean;
    float scl  = pp.g[c] * rsqrtf(var + 1e-5f);
    sSS[side*256 + c] = scl;
    sSS[side*256 + 128 + c] = pp.bn[c] - mean * scl;
  }
  __syncthreads();
  long long tv = nv * 16, total = tv + ne * 16;
  for (long long g = (long long)blockIdx.x * blockDim.x + tid; g < total;
       g += (long long)gridDim.x * blockDim.x){
    bool isv = g < tv;
    char* base = isv ? xv : xe;
    const float* ss = isv ? sSS : (sSS + 256);
    long long gg = isv ? g : g - tv;
    long long row = gg >> 4;
    int c = (int)(gg & 15);
    bf16x8 u = *(const bf16x8*)(base + row * 512 + c * 16);
    int c0 = c * 8;
    float4 o0, o1;
    o0.x = (float)u[0]*ss[c0+0] + ss[128+c0+0];
    o0.y = (float)u[1]*ss[c0+1] + ss[128+c0+1];
    o0.z = (float)u[2]*ss[c0+2] + ss[128+c0+2];
    o0.w = (float)u[3]*ss[c0+3] + ss[128+c0+3];
    o1.x = (float)u[4]*ss[c0+4] + ss[128+c0+4];
    o1.y = (float)u[5]*ss[c0+5] + ss[128+c0+5];
    o1.z = (float)u[6]*ss[c0+6] + ss[128+c0+6];
    o1.w = (float)u[7]*ss[c0+7] + ss[128+c0+7];
    float4* dp = (float4*)(base + row * 512 + c * 32);
    dp[0] = o0; dp[1] = o1;
  }
}

extern "C" void kernel_launch(void* const* d_in, const int* in_sizes, int n_in,
                              void* d_out, int out_size, void* d_ws, size_t ws_size,
                              hipStream_t stream)
{
  const float* v    = (const float*)d_in[0];
  const float* e    = (const float*)d_in[1];
  const float* envl = (const float*)d_in[2];
  const int*   src  = (const int*)d_in[3];
  const int*   dst  = (const int*)d_in[4];
  const float* bOv  = (const float*)d_in[10];
  const float* bOe  = (const float*)d_in[12];
  const float* g1v  = (const float*)d_in[13];
  const float* b1vn = (const float*)d_in[14];
  const float* g1e  = (const float*)d_in[15];
  const float* b1en = (const float*)d_in[16];
  const float* g2v  = (const float*)d_in[17];
  const float* b2vn = (const float*)d_in[18];
  const float* g2e  = (const float*)d_in[19];
  const float* b2en = (const float*)d_in[20];
  const float* b1vf = (const float*)d_in[22];
  const float* b2vf = (const float*)d_in[24];
  const float* b1ef = (const float*)d_in[26];
  const float* b2ef = (const float*)d_in[28];

  float* out_v = (float*)d_out;
  float* out_e = out_v + (size_t)N_NODES * DIM;
  bf16_t* v1b = (bf16_t*)out_v;
  bf16_t* e1b = (bf16_t*)out_e;

  char* ws = (char*)d_ws;
  const size_t IMG_OFF = 0;
  const size_t QB_OFF  = 458752;
  const size_t KB_OFF  = QB_OFF  + 12800000;
  const size_t VB_OFF  = KB_OFF  + 12800000;
  const size_t VA_OFF  = VB_OFF  + 12800000;
  const size_t SV_OFF  = VA_OFF  + 12800000;
  const size_t CSR_OFF = SV_OFF  + 16000000;
  const size_t RP_OFF  = CSR_OFF + 2000000;
  const size_t WP_OFF  = RP_OFF  + 200016;
  const size_t CNT_OFF = WP_OFF  + 200000;
  const size_t ST_OFF  = CNT_OFF + 200000;
  const size_t SS_OFF  = ST_OFF  + 4096;

  char*   img   = ws + IMG_OFF;
  bf16_t* Qb    = (bf16_t*)(ws + QB_OFF);
  bf16_t* Kb    = (bf16_t*)(ws + KB_OFF);
  bf16_t* Vb    = (bf16_t*)(ws + VB_OFF);
  bf16_t* vAttn = (bf16_t*)(ws + VA_OFF);
  float*  svp   = (float*)(ws + SV_OFF);
  int*    csr   = (int*)(ws + CSR_OFF);
  int*    rowp  = (int*)(ws + RP_OFF);
  int*    wpp   = (int*)(ws + WP_OFF);
  int*    cnt   = (int*)(ws + CNT_OFF);
  float*  st    = (float*)(ws + ST_OFF);
  float*  ssb   = (float*)(ws + SS_OFF);
  float* st_e1 = st;        float* st_v1 = st + 256;
  float* st_v2 = st + 512;  float* st_e2 = st + 768;
  float* ss_v1 = ssb;       float* ss_e1 = ssb + 256;

  (void)hipMemsetAsync(ws + CNT_OFF, 0, 200000 + 4096, stream);

  WPrep wp;
  const int wid[10]   = {5,6,7,8,9,11,21,23,25,27};
  const int Ks[10]    = {128,128,128,128,128,128,128,256,128,256};
  const int Ns[10]    = {128,128,128,128,128,128,256,128,256,128};
  const int modes[10] = {1,1,1,1,1,0,4,0,4,0};   // W1: mode-4 per-half; WO_e/W2: mode 0
  int cum = 0, off = 0;
  for (int i = 0; i < 10; i++){
    wp.w[i] = (const float*)d_in[wid[i]];
    wp.Kd[i] = Ks[i]; wp.Nd[i] = Ns[i];
    wp.off[i] = off; wp.cum[i] = cum; wp.mode[i] = modes[i];
    off += Ks[i]*Ns[i]*2; cum += Ks[i]*Ns[i];
  }
  k_wprep<<<896, 256, 0, stream>>>(wp, img, cum);

  k_count<<<1954, 256, 0, stream>>>(dst, cnt);
  k_scan<<<1, 1024, 0, stream>>>(cnt, rowp, wpp);
  k_fill<<<1954, 256, 0, stream>>>(dst, wpp, csr);

  k_qkv<<<391, 512, 0, stream>>>(v, img, Qb, Kb, Vb, N_NODES);

  k_edge<<<1954, 512, 0, stream>>>(e, src, dst, Qb, Kb,
                                   img + 98304 /*We*/, img + 163840 /*WO_e*/, bOe,
                                   e1b, svp, st_e1, N_EDGES);

  k_agg<<<6250, 512, 0, stream>>>(rowp, csr, src, envl, svp, Vb, vAttn, N_NODES);

  k_nodeout<<<391, 512, 0, stream>>>(vAttn, v, img + 131072 /*WO_v*/, bOv,
                                     v1b, st_v1, N_NODES);

  {
    FinArgs fv{st_v1, g1v, b1vn, ss_v1, 1.f / N_NODES};
    FinArgs fe{st_e1, g1e, b1en, ss_e1, 1.f / N_EDGES};
    k_finstats<<<2, 128, 0, stream>>>(fv, fe);
  }

  k_ffn<<<391, 512, 0, stream>>>(v1b, ss_v1, img + 196608 /*W1v*/, b1vf,
                                 img + 262144 /*W2v*/, b2vf, st_v2, N_NODES);
  k_ffn<<<3907, 512, 0, stream>>>(e1b, ss_e1, img + 327680 /*W1e*/, b1ef,
                                  img + 393216 /*W2e*/, b2ef, st_e2, N_EDGES);

  NormP npv{st_v2, g2v, b2vn, 1.f / N_NODES};
  NormP npe{st_e2, g2e, b2en, 1.f / N_EDGES};
  k_norm2<<<4096, 256, 0, stream>>>((char*)out_v, (char*)out_e, npv, npe,
                                    (long long)N_NODES, (long long)N_EDGES);
}

// Round 17
// 616.746 us; speedup vs baseline: 1.1801x; 1.1801x over previous
//
#include <hip/hip_runtime.h>
#include <hip/hip_bf16.h>

#define N_NODES 50000
#define N_EDGES 500000
#define DIM 128
// bf16 row-local intermediates: row i occupies first 256B of the 512B f32 row slot
#define RSTRIDE 256   // elements (bf16) per row slot

typedef __bf16 bf16_t;
typedef __bf16 bf16x8 __attribute__((ext_vector_type(8)));
typedef __bf16 bf16x4 __attribute__((ext_vector_type(4)));
typedef __bf16 bf16x2 __attribute__((ext_vector_type(2)));
typedef float f32x4 __attribute__((ext_vector_type(4)));

#define MFMA(a,b,c) __builtin_amdgcn_mfma_f32_16x16x32_bf16((a),(b),(c),0,0,0)

__device__ __forceinline__ int swz(int row, int kbyte){ return kbyte ^ ((row & 7) << 4); }
__device__ __forceinline__ int hswz(int row, int kbyte){ return kbyte ^ ((row & 15) << 4); }

__device__ __forceinline__ bf16x8 lds_frag(const char* s, int row, int rowb, int kbyte){
  return *(const bf16x8*)(s + row * rowb + swz(row, kbyte));
}

__device__ __forceinline__ void copy16(char* dst, const char* __restrict__ src, int bytes){
  for (int o = threadIdx.x * 16; o < bytes; o += blockDim.x * 16)
    *(f32x4*)(dst + o) = *(const f32x4*)(src + o);
}

// ---------------- weight prep: f32 [K][N] -> bf16 transposed swizzled image [n][k] ----------------
// mode 0: plain transposed image (WO_e, W2v, W2e: A-operands of transposed GEMMs)
// mode 1: permute output-col n -> ((n&7)<<4)|(n>>3)
// mode 4: per-half mode-1 for N=256 (W1): nn = (n>>7)<<7 | ((n&7)<<4) | ((n&127)>>3)
struct WPrep {
  const float* w[10];
  int Kd[10], Nd[10], off[10], cum[10], mode[10];
};

__global__ void k_wprep(WPrep d, char* img, int total){
  for (int idx = blockIdx.x * blockDim.x + threadIdx.x; idx < total; idx += gridDim.x * blockDim.x){
    int i = 0;
#pragma unroll
    for (int j = 1; j < 10; j++) if (idx >= d.cum[j]) i = j;
    int loc = idx - d.cum[i];
    int K = d.Kd[i], N = d.Nd[i];
    int n = loc / K, k = loc - n * K;
    float val = d.w[i][(size_t)k * N + n];
    int nn = n;
    if (d.mode[i] == 1) nn = ((n & 7) << 4) | (n >> 3);
    if (d.mode[i] == 4){ int w7 = n & 127; nn = ((n >> 7) << 7) | ((w7 & 7) << 4) | (w7 >> 3); }
    *(bf16_t*)(img + d.off[i] + nn * (K * 2) + swz(nn, k * 2)) = (bf16_t)val;
  }
}

// ---------------- CSR build ----------------
__global__ void k_count(const int* __restrict__ dst, int* __restrict__ cnt){
  int i = blockIdx.x * blockDim.x + threadIdx.x;
  if (i < N_EDGES) atomicAdd(&cnt[dst[i]], 1);
}

__global__ __launch_bounds__(1024) void k_scan(const int* __restrict__ cnt,
                                               int* __restrict__ rowptr, int* __restrict__ wp){
  __shared__ int wsum[16];
  __shared__ int wpre[16];
  __shared__ int scarry;
  const int tid = threadIdx.x, lane = tid & 63, wv = tid >> 6;
  if (tid == 0) scarry = 0;
  for (int base = 0; base < N_NODES; base += 8192){
    int i0 = base + tid * 8;
    int v[8], p[8];
    int tsum = 0;
#pragma unroll
    for (int j = 0; j < 8; j++){
      int idx = i0 + j;
      v[j] = (idx < N_NODES) ? cnt[idx] : 0;
      p[j] = tsum; tsum += v[j];
    }
    int x = tsum;
#pragma unroll
    for (int off = 1; off < 64; off <<= 1){
      int t = __shfl_up(x, off);
      if (lane >= off) x += t;
    }
    if (lane == 63) wsum[wv] = x;
    __syncthreads();
    if (tid == 0){
      int run = scarry;
#pragma unroll
      for (int j = 0; j < 16; j++){ int t = wsum[j]; wpre[j] = run; run += t; }
      scarry = run;
    }
    __syncthreads();
    int texcl = wpre[wv] + x - tsum;
#pragma unroll
    for (int j = 0; j < 8; j++){
      int idx = i0 + j;
      if (idx < N_NODES){ rowptr[idx] = texcl + p[j]; wp[idx] = texcl + p[j]; }
    }
    __syncthreads();
  }
  if (tid == 0) rowptr[N_NODES] = scarry;
}

__global__ void k_fill(const int* __restrict__ dst, int* __restrict__ wp, int* __restrict__ csr){
  int i = blockIdx.x * blockDim.x + threadIdx.x;
  if (i < N_EDGES){
    int p = atomicAdd(&wp[dst[i]], 1);
    csr[p] = i;
  }
}

// ---------------- QKV: [M,128] @ 3x [128,128] -> bf16 outputs (mode-1 weights) ----------------
__global__ __launch_bounds__(512) void k_qkv(
    const float* __restrict__ v, const char* __restrict__ img,
    bf16_t* __restrict__ Q, bf16_t* __restrict__ K, bf16_t* __restrict__ V, int M)
{
  __shared__ __align__(16) char sm[65536];
  char* sX = sm;
  char* sW = sm + 32768;
  const int tid = threadIdx.x, lane = tid & 63, wave = tid >> 6;
  const int r0 = blockIdx.x * 128;
  for (int c = tid; c < 2048; c += 512){
    int row = c >> 4, kc = c & 15, grow = r0 + row;
    float f[8];
    if (grow < M){
      const float4* p = (const float4*)(v + (size_t)grow * DIM + kc * 8);
      float4 u0 = p[0], u1 = p[1];
      f[0]=u0.x; f[1]=u0.y; f[2]=u0.z; f[3]=u0.w;
      f[4]=u1.x; f[5]=u1.y; f[6]=u1.z; f[7]=u1.w;
    } else {
#pragma unroll
      for (int j=0;j<8;j++) f[j] = 0.f;
    }
    bf16x8 o;
#pragma unroll
    for (int j=0;j<8;j++) o[j] = (bf16_t)f[j];
    *(bf16x8*)(sX + row * 256 + swz(row, kc * 16)) = o;
  }
  const int rowA = wave * 16 + (lane & 15);
  const int kb0 = (lane >> 4) * 16;
  const int crow = wave*16 + (lane >> 4)*4;
  const int ccol = lane & 15;
  const f32x4 zero4 = {0.f, 0.f, 0.f, 0.f};
#pragma unroll
  for (int w3 = 0; w3 < 3; w3++){
    __syncthreads();
    copy16(sW, img + w3 * 32768, 32768);
    __syncthreads();
    f32x4 acc[8];
#pragma unroll
    for (int b=0;b<8;b++) acc[b] = zero4;
#pragma unroll
    for (int ks=0; ks<4; ks++){
      bf16x8 a = lds_frag(sX, rowA, 256, ks*64 + kb0);
#pragma unroll
      for (int nt=0; nt<8; nt++){
        int rn = nt*16 + (lane & 15);
        bf16x8 b = lds_frag(sW, rn, 256, ks*64 + kb0);
        acc[nt] = MFMA(a, b, acc[nt]);
      }
    }
    bf16_t* o = (w3 == 0) ? Q : ((w3 == 1) ? K : V);
#pragma unroll
    for (int r=0; r<4; r++){
      int grow = r0 + crow + r;
      if (grow < M){
        bf16x8 t;
#pragma unroll
        for (int nt=0; nt<8; nt++) t[nt] = (bf16_t)acc[nt][r];
        *(bf16x8*)(o + (size_t)grow * DIM + ccol*8) = t;
      }
    }
  }
}

// ---------------- fused edge attention: transposed GEMM2; residual served from LDS ----------------
__global__ __launch_bounds__(512, 4) void k_edge(
    const float* __restrict__ e,
    const int* __restrict__ src, const int* __restrict__ dst,
    const bf16_t* __restrict__ Qb, const bf16_t* __restrict__ Kb,
    const char* __restrict__ imgWe, const char* __restrict__ imgWo,
    const float* __restrict__ bOe,
    bf16_t* __restrict__ e1_pre, float* __restrict__ sv,
    float* __restrict__ stats, int M)
{
  __shared__ __align__(16) char sm[66560];
  char* sBuf = sm;                        // We, then score
  char* sE   = sm + 32768;                // bf16 e tile (residual source)
  float* sStats = (float*)(sm + 65536);
  const int tid = threadIdx.x, lane = tid & 63, wave = tid >> 6;
  const int r0 = blockIdx.x * 128;
  const int q = lane >> 4, ccol = lane & 15;
  const int crow = wave*16 + q*4;
  const int rowA = wave*16 + ccol;
  const int kb0 = q * 16;
  bf16x8 Kg[4], Qg[4];
#pragma unroll
  for (int r=0;r<4;r++){
    int ed = r0 + crow + r; if (ed >= M) ed = M - 1;
    int sn = src[ed], dn = dst[ed];
    Kg[r] = *(const bf16x8*)(Kb + (size_t)sn * DIM + ccol * 8);
    Qg[r] = *(const bf16x8*)(Qb + (size_t)dn * DIM + ccol * 8);
  }
  int grA = r0 + rowA; if (grA >= M) grA = M - 1;
  const f32x4* epA = (const f32x4*)(e + (size_t)grA * DIM);
  f32x4 ea[8];
#pragma unroll
  for (int ks=0; ks<4; ks++){
    ea[2*ks]   = epA[ks*8 + q*2];
    ea[2*ks+1] = epA[ks*8 + q*2 + 1];
  }
  copy16(sBuf, imgWe, 32768);
  bf16x8 eAb[4];
#pragma unroll
  for (int ks=0; ks<4; ks++){
#pragma unroll
    for (int j=0;j<4;j++){
      eAb[ks][j]   = (bf16_t)ea[2*ks][j];
      eAb[ks][4+j] = (bf16_t)ea[2*ks+1][j];
    }
  }
  // stash bf16 e row in sE (residual served from LDS in the epilogue)
#pragma unroll
  for (int ks=0; ks<4; ks++)
    *(bf16x8*)(sE + rowA*256 + swz(rowA, ks*64 + kb0)) = eAb[ks];
  __syncthreads();   // B1: We + sE staged
  const f32x4 zero4 = {0.f,0.f,0.f,0.f};
  f32x4 pe[8];
#pragma unroll
  for (int i=0;i<8;i++) pe[i] = zero4;
#pragma unroll
  for (int ks=0; ks<4; ks++){
#pragma unroll
    for (int nt=0; nt<8; nt++){
      bf16x8 b = lds_frag(sBuf, nt*16 + ccol, 256, ks*64 + kb0);
      pe[nt] = MFMA(eAb[ks], b, pe[nt]);
    }
  }
  __syncthreads();   // B2
#pragma unroll
  for (int r=0;r<4;r++){
    int row = crow + r;
    bf16x8 t;
    float hsum = 0.f;
#pragma unroll
    for (int nt=0; nt<8; nt++){
      float sc = pe[nt][r] * 0.25f * (float)Kg[r][nt] * (float)Qg[r][nt];
      t[nt] = (bf16_t)sc;
      hsum += sc;
    }
    *(bf16x8*)(sBuf + row*256 + swz(row, ccol*16)) = t;
    float ts = hsum + __shfl_xor(hsum, 1);
    int ed = r0 + row;
    if (!(ccol & 1) && ed < M)
      sv[(size_t)ed*8 + (ccol >> 1)] = __expf(fminf(5.f, fmaxf(-5.f, ts)));
  }
  bf16x8 w2a[4];
#pragma unroll
  for (int ks=0; ks<4; ks++)
    w2a[ks] = *(const bf16x8*)(imgWo + rowA*256 + swz(rowA, ks*64 + kb0));
  __syncthreads();   // B3: score staged
  f32x4 a2[8];
#pragma unroll
  for (int i=0;i<8;i++) a2[i] = zero4;
#pragma unroll
  for (int ks=0; ks<4; ks++){
#pragma unroll
    for (int nt=0; nt<8; nt++){
      bf16x8 b = lds_frag(sBuf, nt*16 + ccol, 256, ks*64 + kb0);
      a2[nt] = MFMA(w2a[ks], b, a2[nt]);
    }
  }
  // epilogue: residual from sE (bf16), transposed footprint
  float4 bo = *(const float4*)(bOe + crow);
  float s1[4] = {0.f,0.f,0.f,0.f}, s2[4] = {0.f,0.f,0.f,0.f};
#pragma unroll
  for (int nt=0; nt<8; nt++){
    int m = nt*16 + ccol;
    int erow = r0 + m;
    bf16x4 u = *(const bf16x4*)(sE + m*256 + swz(m, crow*2));
    float val[4];
    val[0] = a2[nt][0] + (float)u[0] + bo.x;
    val[1] = a2[nt][1] + (float)u[1] + bo.y;
    val[2] = a2[nt][2] + (float)u[2] + bo.z;
    val[3] = a2[nt][3] + (float)u[3] + bo.w;
    if (erow < M){
      bf16x4 t;
#pragma unroll
      for (int r=0;r<4;r++) t[r] = (bf16_t)val[r];
      *(bf16x4*)(e1_pre + (size_t)erow*RSTRIDE + crow) = t;
    } else {
#pragma unroll
      for (int r=0;r<4;r++) val[r] = 0.f;
    }
#pragma unroll
    for (int r=0;r<4;r++){ s1[r] += val[r]; s2[r] += val[r]*val[r]; }
  }
#pragma unroll
  for (int r=0;r<4;r++){
    s1[r] += __shfl_xor(s1[r], 1); s1[r] += __shfl_xor(s1[r], 2);
    s1[r] += __shfl_xor(s1[r], 4); s1[r] += __shfl_xor(s1[r], 8);
    s2[r] += __shfl_xor(s2[r], 1); s2[r] += __shfl_xor(s2[r], 2);
    s2[r] += __shfl_xor(s2[r], 4); s2[r] += __shfl_xor(s2[r], 8);
  }
  if (ccol == 0){
#pragma unroll
    for (int r=0;r<4;r++){
      sStats[crow + r] = s1[r];
      sStats[128 + crow + r] = s2[r];
    }
  }
  __syncthreads();
  if (tid < 256) unsafeAtomicAdd(&stats[tid], sStats[tid]);
}

// ---------------- aggregation: one wave per node, CSR walk, 4-deep pipelined ----------------
__global__ __launch_bounds__(512) void k_agg(
    const int* __restrict__ rowptr, const int* __restrict__ csr,
    const int* __restrict__ src, const float* __restrict__ envl,
    const float* __restrict__ sv, const bf16_t* __restrict__ V,
    bf16_t* __restrict__ vAttn, int M)
{
  const int wave = threadIdx.x >> 6, lane = threadIdx.x & 63;
  const int n = blockIdx.x * 8 + wave;
  if (n >= M) return;
  const int beg = rowptr[n], end = rowptr[n + 1];
  const int h = lane >> 3;
  float ax = 0.f, ay = 0.f, zacc = 0.f;
  int i = beg;
  for (; i + 4 <= end; i += 4){
    int e0 = csr[i], e1 = csr[i+1], e2 = csr[i+2], e3 = csr[i+3];
    int sn0 = src[e0], sn1 = src[e1], sn2 = src[e2], sn3 = src[e3];
    float sv0 = sv[(size_t)e0*8 + h], sv1 = sv[(size_t)e1*8 + h];
    float sv2 = sv[(size_t)e2*8 + h], sv3 = sv[(size_t)e3*8 + h];
    float n0 = envl[e0], n1 = envl[e1], n2 = envl[e2], n3 = envl[e3];
    bf16x2 a0 = *(const bf16x2*)(V + (size_t)sn0 * DIM + lane * 2);
    bf16x2 a1 = *(const bf16x2*)(V + (size_t)sn1 * DIM + lane * 2);
    bf16x2 a2v = *(const bf16x2*)(V + (size_t)sn2 * DIM + lane * 2);
    bf16x2 a3 = *(const bf16x2*)(V + (size_t)sn3 * DIM + lane * 2);
    float w0 = n0*sv0, w1 = n1*sv1, w2 = n2*sv2, w3 = n3*sv3;
    ax += (float)a0[0]*w0 + (float)a1[0]*w1 + (float)a2v[0]*w2 + (float)a3[0]*w3;
    ay += (float)a0[1]*w0 + (float)a1[1]*w1 + (float)a2v[1]*w2 + (float)a3[1]*w3;
    zacc += sv0 + sv1 + sv2 + sv3;
  }
  for (; i < end; i++){
    int eid = csr[i];
    int sn = src[eid];
    float s = sv[(size_t)eid * 8 + h];
    float env = envl[eid];
    const bf16x2 vv = *(const bf16x2*)(V + (size_t)sn * DIM + lane * 2);
    float w = env * s;
    ax += (float)vv[0] * w; ay += (float)vv[1] * w;
    zacc += s;
  }
  float inv = 1.f / (zacc + 1e-6f);
  bf16x2 o; o[0] = (bf16_t)(ax * inv); o[1] = (bf16_t)(ay * inv);
  *(bf16x2*)(vAttn + (size_t)n * DIM + lane * 2) = o;
}

// ---------------- node out-proj (bf16 row-local write; stats) ----------------
__global__ __launch_bounds__(512) void k_nodeout(
    const bf16_t* __restrict__ vAttn, const float* __restrict__ v,
    const char* __restrict__ imgWo, const float* __restrict__ bOv,
    bf16_t* __restrict__ v1_pre, float* __restrict__ stats, int M)
{
  __shared__ __align__(16) char sm[66560];
  char* sW = sm;
  char* sX = sm + 32768;
  float* sStats = (float*)(sm + 65536);
  const int tid = threadIdx.x, lane = tid & 63, wave = tid >> 6;
  const int r0 = blockIdx.x * 128;
  copy16(sW, imgWo, 32768);
  if (tid < 256) sStats[tid] = 0.f;
  for (int c = tid; c < 2048; c += 512){
    int row = c >> 4, kc = c & 15, grow = r0 + row;
    bf16x8 o;
    if (grow < M){
      o = *(const bf16x8*)(vAttn + (size_t)grow * DIM + kc * 8);
    } else {
#pragma unroll
      for (int j=0;j<8;j++) o[j] = (bf16_t)0.f;
    }
    *(bf16x8*)(sX + row*256 + swz(row, kc*16)) = o;
  }
  __syncthreads();
  const int rowA = wave*16 + (lane & 15);
  const int kb0 = (lane >> 4)*16;
  const f32x4 zero4 = {0.f,0.f,0.f,0.f};
  f32x4 acc[8];
#pragma unroll
  for (int i=0;i<8;i++) acc[i]=zero4;
#pragma unroll
  for (int ks=0;ks<4;ks++){
    bf16x8 a = lds_frag(sX, rowA, 256, ks*64+kb0);
#pragma unroll
    for (int nt=0;nt<8;nt++){
      int rn = nt*16 + (lane&15);
      bf16x8 b = lds_frag(sW, rn, 256, ks*64+kb0);
      acc[nt] = MFMA(a,b,acc[nt]);
    }
  }
  const int crow = wave*16 + (lane>>4)*4;
  const int ccol = lane & 15;
  float4 bo0 = *(const float4*)(bOv + ccol*8);
  float4 bo1 = *(const float4*)(bOv + ccol*8 + 4);
  float s1[8], s2[8];
#pragma unroll
  for (int j=0;j<8;j++){ s1[j]=0.f; s2[j]=0.f; }
#pragma unroll
  for (int r=0;r<4;r++){
    int grow = r0 + crow + r;
    float val[8];
    if (grow < M){
      const float4* vp = (const float4*)(v + (size_t)grow*DIM + ccol*8);
      float4 v0 = vp[0], v1 = vp[1];
      val[0]=acc[0][r]+v0.x+bo0.x; val[1]=acc[1][r]+v0.y+bo0.y;
      val[2]=acc[2][r]+v0.z+bo0.z; val[3]=acc[3][r]+v0.w+bo0.w;
      val[4]=acc[4][r]+v1.x+bo1.x; val[5]=acc[5][r]+v1.y+bo1.y;
      val[6]=acc[6][r]+v1.z+bo1.z; val[7]=acc[7][r]+v1.w+bo1.w;
      bf16x8 t;
#pragma unroll
      for (int j=0;j<8;j++) t[j] = (bf16_t)val[j];
      *(bf16x8*)(v1_pre + (size_t)grow*RSTRIDE + ccol*8) = t;
    } else {
#pragma unroll
      for (int j=0;j<8;j++) val[j]=0.f;
    }
#pragma unroll
    for (int j=0;j<8;j++){ s1[j] += val[j]; s2[j] += val[j]*val[j]; }
  }
#pragma unroll
  for (int j=0;j<8;j++){
    s1[j] += __shfl_xor(s1[j], 16); s1[j] += __shfl_xor(s1[j], 32);
    s2[j] += __shfl_xor(s2[j], 16); s2[j] += __shfl_xor(s2[j], 32);
  }
  if (lane < 16){
#pragma unroll
    for (int j=0;j<8;j++){
      atomicAdd(&sStats[ccol*8 + j], s1[j]);
      atomicAdd(&sStats[128 + ccol*8 + j], s2[j]);
    }
  }
  __syncthreads();
  if (tid < 256) unsafeAtomicAdd(&stats[tid], sStats[tid]);
}

// ---------------- stats -> scale/shift (BN1) ----------------
struct FinArgs { const float* st; const float* g; const float* b; float* ss; float invM; };

__global__ void k_finstats(FinArgs a0, FinArgs a1){
  FinArgs a = (blockIdx.x == 0) ? a0 : a1;
  int c = threadIdx.x;
  float mean = a.st[c] * a.invM;
  float var  = a.st[128 + c] * a.invM - mean * mean;
  float scl  = a.g[c] * rsqrtf(var + 1e-5f);
  a.ss[c] = scl;
  a.ss[128 + c] = a.b[c] - mean * scl;
}

// ---------------- fused FFN: dual buffer, transposed GEMM2', 6 barriers, (512,4) no-spill ----------------
__global__ __launch_bounds__(512, 4) void k_ffn(
    bf16_t* __restrict__ xio, const float* __restrict__ ss1,
    const char* __restrict__ img1, const float* __restrict__ b1,
    const char* __restrict__ img2, const float* __restrict__ b2,
    float* __restrict__ stats2, int M)
{
  __shared__ __align__(16) char sm[66560];
  char* sA = sm;            // h k-half (hswz layout)
  char* sB = sm + 32768;    // W1h0 -> W1h1 -> o2^T
  float* sStats = (float*)(sm + 65536);
  const int tid = threadIdx.x, lane = tid & 63, wave = tid >> 6;
  const int r0 = blockIdx.x * 128;
  const int q = lane >> 4, ccol = lane & 15;
  const int kb0 = q * 16;
  const int crow = wave*16 + q*4;
  const int rowA = wave*16 + ccol;
  const f32x4 zero4 = {0.f,0.f,0.f,0.f};

  // phase A: W1 half0 -> sB; x row frags + inline BN
  copy16(sB, img1, 32768);
  if (tid < 256) sStats[tid] = 0.f;
  int grA = r0 + rowA; if (grA >= M) grA = M - 1;
  const bf16_t* xrow = xio + (size_t)grA * RSTRIDE;
  bf16x8 araw[4];
#pragma unroll
  for (int ks=0; ks<4; ks++)
    araw[ks] = *(const bf16x8*)(xrow + ks*32 + q*8);
  bf16x8 xAb[4];
#pragma unroll
  for (int ks=0; ks<4; ks++){
    const f32x4* sp = (const f32x4*)(ss1 + ks*32 + q*8);
    const f32x4* hp = (const f32x4*)(ss1 + 128 + ks*32 + q*8);
    f32x4 s0 = sp[0], s1v = sp[1], h0 = hp[0], h1 = hp[1];
#pragma unroll
    for (int j=0;j<4;j++){
      xAb[ks][j]   = (bf16_t)((float)araw[ks][j]  *s0[j]  + h0[j]);
      xAb[ks][4+j] = (bf16_t)((float)araw[ks][4+j]*s1v[j] + h1[j]);
    }
  }
  __syncthreads();  // B1: W1h0 ready

  bf16x8 hreg0[4], hreg1[4];
  f32x4 wbuf[4];
#pragma unroll
  for (int i=0;i<4;i++) wbuf[i] = *(const f32x4*)(img1 + 32768 + tid*16 + i*8192);
  // GEMM1a: hcols ccol*8+nt (k-half0)
  {
    float4 bq0 = *(const float4*)(b1 + ccol*8);
    float4 bq1 = *(const float4*)(b1 + ccol*8 + 4);
    f32x4 acc[8];
#pragma unroll
    for (int i=0;i<8;i++) acc[i]=zero4;
#pragma unroll
    for (int ks=0;ks<4;ks++){
#pragma unroll
      for (int nt=0;nt<8;nt++){
        bf16x8 b = lds_frag(sB, nt*16 + ccol, 256, ks*64+kb0);
        acc[nt] = MFMA(xAb[ks], b, acc[nt]);
      }
    }
#pragma unroll
    for (int r=0;r<4;r++){
      bf16x8 t;
      t[0]=(bf16_t)fmaxf(acc[0][r]+bq0.x,0.f); t[1]=(bf16_t)fmaxf(acc[1][r]+bq0.y,0.f);
      t[2]=(bf16_t)fmaxf(acc[2][r]+bq0.z,0.f); t[3]=(bf16_t)fmaxf(acc[3][r]+bq0.w,0.f);
      t[4]=(bf16_t)fmaxf(acc[4][r]+bq1.x,0.f); t[5]=(bf16_t)fmaxf(acc[5][r]+bq1.y,0.f);
      t[6]=(bf16_t)fmaxf(acc[6][r]+bq1.z,0.f); t[7]=(bf16_t)fmaxf(acc[7][r]+bq1.w,0.f);
      hreg0[r] = t;
    }
  }
  __syncthreads();  // B2: done reading sB (W1h0)
  // write W1h1 -> sB and h0 -> sA
#pragma unroll
  for (int i=0;i<4;i++) *(f32x4*)(sB + tid*16 + i*8192) = wbuf[i];
#pragma unroll
  for (int r=0;r<4;r++){
    int row = crow + r;
    *(bf16x8*)(sA + row*256 + hswz(row, ccol*16)) = hreg0[r];
  }
  __syncthreads();  // B3: W1h1 + h0 ready (hreg0 dead)

  f32x4 o2[8];
#pragma unroll
  for (int i=0;i<8;i++) o2[i]=zero4;
  // GEMM1b: hcols 128+ccol*8+nt (reads sB)
  {
    float4 bq2 = *(const float4*)(b1 + 128 + ccol*8);
    float4 bq3 = *(const float4*)(b1 + 128 + ccol*8 + 4);
    f32x4 acc[8];
#pragma unroll
    for (int i=0;i<8;i++) acc[i]=zero4;
#pragma unroll
    for (int ks=0;ks<4;ks++){
#pragma unroll
      for (int nt=0;nt<8;nt++){
        bf16x8 b = lds_frag(sB, nt*16 + ccol, 256, ks*64+kb0);
        acc[nt] = MFMA(xAb[ks], b, acc[nt]);
      }
    }
#pragma unroll
    for (int r=0;r<4;r++){
      bf16x8 t;
      t[0]=(bf16_t)fmaxf(acc[0][r]+bq2.x,0.f); t[1]=(bf16_t)fmaxf(acc[1][r]+bq2.y,0.f);
      t[2]=(bf16_t)fmaxf(acc[2][r]+bq2.z,0.f); t[3]=(bf16_t)fmaxf(acc[3][r]+bq2.w,0.f);
      t[4]=(bf16_t)fmaxf(acc[4][r]+bq3.x,0.f); t[5]=(bf16_t)fmaxf(acc[5][r]+bq3.y,0.f);
      t[6]=(bf16_t)fmaxf(acc[6][r]+bq3.z,0.f); t[7]=(bf16_t)fmaxf(acc[7][r]+bq3.w,0.f);
      hreg1[r] = t;
    }
  }
  // GEMM2'a over k-half0 (reads sA; no barrier needed — read-read with GEMM1b)
  {
    bf16x8 w2a[4];
#pragma unroll
    for (int ks=0; ks<4; ks++)
      w2a[ks] = *(const bf16x8*)(img2 + (size_t)rowA*512 + swz(rowA, ks*64 + kb0));
#pragma unroll
    for (int ks=0; ks<4; ks++){
#pragma unroll
      for (int nt=0; nt<8; nt++){
        int m = nt*16 + ccol;
        bf16x8 b = *(const bf16x8*)(sA + m*256 + hswz(m, ks*64 + kb0));
        o2[nt] = MFMA(w2a[ks], b, o2[nt]);
      }
    }
  }
  __syncthreads();  // B4: done reading sA (h0) and sB (W1h1)
#pragma unroll
  for (int r=0;r<4;r++){
    int row = crow + r;
    *(bf16x8*)(sA + row*256 + hswz(row, ccol*16)) = hreg1[r];
  }
  __syncthreads();  // B5: h1 ready (hreg1 dead)
  // GEMM2'b over k-half1
  {
    bf16x8 w2a[4];
#pragma unroll
    for (int ks=0; ks<4; ks++)
      w2a[ks] = *(const bf16x8*)(img2 + (size_t)rowA*512 + swz(rowA, 256 + ks*64 + kb0));
#pragma unroll
    for (int ks=0; ks<4; ks++){
#pragma unroll
      for (int nt=0; nt<8; nt++){
        int m = nt*16 + ccol;
        bf16x8 b = *(const bf16x8*)(sA + m*256 + hswz(m, ks*64 + kb0));
        o2[nt] = MFMA(w2a[ks], b, o2[nt]);
      }
    }
  }
  // o2 -> bf16, transposed into sB (free since B4): row m = nt*16+ccol, cols crow..+3
#pragma unroll
  for (int nt=0; nt<8; nt++){
    int m = nt*16 + ccol;
    bf16x4 t;
#pragma unroll
    for (int r=0;r<4;r++) t[r] = (bf16_t)o2[nt][r];
    *(bf16x4*)(sB + m*256 + swz(m, crow*2)) = t;
  }
  __syncthreads();  // B6: o2^T staged

  // row-major epilogue: rows crow..+3, cols ccol*8..+7
  float4 sc0 = *(const float4*)(ss1 + ccol*8);
  float4 sc1 = *(const float4*)(ss1 + ccol*8 + 4);
  float4 sh0 = *(const float4*)(ss1 + 128 + ccol*8);
  float4 sh1 = *(const float4*)(ss1 + 128 + ccol*8 + 4);
  float4 b20 = *(const float4*)(b2 + ccol*8);
  float4 b21 = *(const float4*)(b2 + ccol*8 + 4);
  float s1[8], s2[8];
#pragma unroll
  for (int j=0;j<8;j++){ s1[j]=0.f; s2[j]=0.f; }
#pragma unroll
  for (int r=0;r<4;r++){
    int row = crow + r, grow = r0 + row;
    float val[8];
    if (grow < M){
      bf16x8 u = *(const bf16x8*)(xio + (size_t)grow*RSTRIDE + ccol*8);
      bf16x8 ob = *(const bf16x8*)(sB + row*256 + swz(row, ccol*16));
      val[0]=(float)u[0]*sc0.x+sh0.x + (float)ob[0]+b20.x;
      val[1]=(float)u[1]*sc0.y+sh0.y + (float)ob[1]+b20.y;
      val[2]=(float)u[2]*sc0.z+sh0.z + (float)ob[2]+b20.z;
      val[3]=(float)u[3]*sc0.w+sh0.w + (float)ob[3]+b20.w;
      val[4]=(float)u[4]*sc1.x+sh1.x + (float)ob[4]+b21.x;
      val[5]=(float)u[5]*sc1.y+sh1.y + (float)ob[5]+b21.y;
      val[6]=(float)u[6]*sc1.z+sh1.z + (float)ob[6]+b21.z;
      val[7]=(float)u[7]*sc1.w+sh1.w + (float)ob[7]+b21.w;
      bf16x8 t;
#pragma unroll
      for (int j=0;j<8;j++) t[j] = (bf16_t)val[j];
      *(bf16x8*)(xio + (size_t)grow*RSTRIDE + ccol*8) = t;
    } else {
#pragma unroll
      for (int j=0;j<8;j++) val[j]=0.f;
    }
#pragma unroll
    for (int j=0;j<8;j++){ s1[j] += val[j]; s2[j] += val[j]*val[j]; }
  }
#pragma unroll
  for (int j=0;j<8;j++){
    s1[j] += __shfl_xor(s1[j], 16); s1[j] += __shfl_xor(s1[j], 32);
    s2[j] += __shfl_xor(s2[j], 16); s2[j] += __shfl_xor(s2[j], 32);
  }
  if (lane < 16){
#pragma unroll
    for (int j=0;j<8;j++){
      atomicAdd(&sStats[ccol*8 + j], s1[j]);
      atomicAdd(&sStats[128 + ccol*8 + j], s2[j]);
    }
  }
  __syncthreads();  // B7
  if (tid < 256) unsafeAtomicAdd(&stats2[tid], sStats[tid]);
}

// ---------------- in-place bf16->f32 normalize-expand (in-block BN2 finalize) ----------------
struct NormP { const float* st; const float* g; const float* bn; float invM; };

__global__ __launch_bounds__(256) void k_norm2(
    char* __restrict__ xv, char* __restrict__ xe,
    NormP pv, NormP pe, long long nv, long long ne)
{
  __shared__ float sSS[512];
  const int tid = threadIdx.x;
  {
    int side = tid >> 7, c = tid & 127;
    NormP pp = side ? pe : pv;
    float mean = pp.st[c] * pp.invM;
    float var  = pp.st[128 + c] * pp.invM - mean * mean;
    float scl  = pp.g[c] * rsqrtf(var + 1e-5f);
    sSS[side*256 + c] = scl;
    sSS[side*256 + 128 + c] = pp.bn[c] - mean * scl;
  }
  __syncthreads();
  long long tv = nv * 16, total = tv + ne * 16;
  for (long long g = (long long)blockIdx.x * blockDim.x + tid; g < total;
       g += (long long)gridDim.x * blockDim.x){
    bool isv = g < tv;
    char* base = isv ? xv : xe;
    const float* ss = isv ? sSS : (sSS + 256);
    long long gg = isv ? g : g - tv;
    long long row = gg >> 4;
    int c = (int)(gg & 15);
    bf16x8 u = *(const bf16x8*)(base + row * 512 + c * 16);
    int c0 = c * 8;
    float4 o0, o1;
    o0.x = (float)u[0]*ss[c0+0] + ss[128+c0+0];
    o0.y = (float)u[1]*ss[c0+1] + ss[128+c0+1];
    o0.z = (float)u[2]*ss[c0+2] + ss[128+c0+2];
    o0.w = (float)u[3]*ss[c0+3] + ss[128+c0+3];
    o1.x = (float)u[4]*ss[c0+4] + ss[128+c0+4];
    o1.y = (float)u[5]*ss[c0+5] + ss[128+c0+5];
    o1.z = (float)u[6]*ss[c0+6] + ss[128+c0+6];
    o1.w = (float)u[7]*ss[c0+7] + ss[128+c0+7];
    float4* dp = (float4*)(base + row * 512 + c * 32);
    dp[0] = o0; dp[1] = o1;
  }
}

extern "C" void kernel_launch(void* const* d_in, const int* in_sizes, int n_in,
                              void* d_out, int out_size, void* d_ws, size_t ws_size,
                              hipStream_t stream)
{
  const float* v    = (const float*)d_in[0];
  const float* e    = (const float*)d_in[1];
  const float* envl = (const float*)d_in[2];
  const int*   src  = (const int*)d_in[3];
  const int*   dst  = (const int*)d_in[4];
  const float* bOv  = (const float*)d_in[10];
  const float* bOe  = (const float*)d_in[12];
  const float* g1v  = (const float*)d_in[13];
  const float* b1vn = (const float*)d_in[14];
  const float* g1e  = (const float*)d_in[15];
  const float* b1en = (const float*)d_in[16];
  const float* g2v  = (const float*)d_in[17];
  const float* b2vn = (const float*)d_in[18];
  const float* g2e  = (const float*)d_in[19];
  const float* b2en = (const float*)d_in[20];
  const float* b1vf = (const float*)d_in[22];
  const float* b2vf = (const float*)d_in[24];
  const float* b1ef = (const float*)d_in[26];
  const float* b2ef = (const float*)d_in[28];

  float* out_v = (float*)d_out;
  float* out_e = out_v + (size_t)N_NODES * DIM;
  bf16_t* v1b = (bf16_t*)out_v;
  bf16_t* e1b = (bf16_t*)out_e;

  char* ws = (char*)d_ws;
  const size_t IMG_OFF = 0;
  const size_t QB_OFF  = 458752;
  const size_t KB_OFF  = QB_OFF  + 12800000;
  const size_t VB_OFF  = KB_OFF  + 12800000;
  const size_t VA_OFF  = VB_OFF  + 12800000;
  const size_t SV_OFF  = VA_OFF  + 12800000;
  const size_t CSR_OFF = SV_OFF  + 16000000;
  const size_t RP_OFF  = CSR_OFF + 2000000;
  const size_t WP_OFF  = RP_OFF  + 200016;
  const size_t CNT_OFF = WP_OFF  + 200000;
  const size_t ST_OFF  = CNT_OFF + 200000;
  const size_t SS_OFF  = ST_OFF  + 4096;

  char*   img   = ws + IMG_OFF;
  bf16_t* Qb    = (bf16_t*)(ws + QB_OFF);
  bf16_t* Kb    = (bf16_t*)(ws + KB_OFF);
  bf16_t* Vb    = (bf16_t*)(ws + VB_OFF);
  bf16_t* vAttn = (bf16_t*)(ws + VA_OFF);
  float*  svp   = (float*)(ws + SV_OFF);
  int*    csr   = (int*)(ws + CSR_OFF);
  int*    rowp  = (int*)(ws + RP_OFF);
  int*    wpp   = (int*)(ws + WP_OFF);
  int*    cnt   = (int*)(ws + CNT_OFF);
  float*  st    = (float*)(ws + ST_OFF);
  float*  ssb   = (float*)(ws + SS_OFF);
  float* st_e1 = st;        float* st_v1 = st + 256;
  float* st_v2 = st + 512;  float* st_e2 = st + 768;
  float* ss_v1 = ssb;       float* ss_e1 = ssb + 256;

  (void)hipMemsetAsync(ws + CNT_OFF, 0, 200000 + 4096, stream);

  WPrep wp;
  const int wid[10]   = {5,6,7,8,9,11,21,23,25,27};
  const int Ks[10]    = {128,128,128,128,128,128,128,256,128,256};
  const int Ns[10]    = {128,128,128,128,128,128,256,128,256,128};
  const int modes[10] = {1,1,1,1,1,0,4,0,4,0};   // W1: mode-4 per-half; WO_e/W2: mode 0
  int cum = 0, off = 0;
  for (int i = 0; i < 10; i++){
    wp.w[i] = (const float*)d_in[wid[i]];
    wp.Kd[i] = Ks[i]; wp.Nd[i] = Ns[i];
    wp.off[i] = off; wp.cum[i] = cum; wp.mode[i] = modes[i];
    off += Ks[i]*Ns[i]*2; cum += Ks[i]*Ns[i];
  }
  k_wprep<<<896, 256, 0, stream>>>(wp, img, cum);

  k_count<<<1954, 256, 0, stream>>>(dst, cnt);
  k_scan<<<1, 1024, 0, stream>>>(cnt, rowp, wpp);
  k_fill<<<1954, 256, 0, stream>>>(dst, wpp, csr);

  k_qkv<<<391, 512, 0, stream>>>(v, img, Qb, Kb, Vb, N_NODES);

  k_edge<<<3907, 512, 0, stream>>>(e, src, dst, Qb, Kb,
                                   img + 98304 /*We*/, img + 163840 /*WO_e*/, bOe,
                                   e1b, svp, st_e1, N_EDGES);

  k_agg<<<6250, 512, 0, stream>>>(rowp, csr, src, envl, svp, Vb, vAttn, N_NODES);

  k_nodeout<<<391, 512, 0, stream>>>(vAttn, v, img + 131072 /*WO_v*/, bOv,
                                     v1b, st_v1, N_NODES);

  {
    FinArgs fv{st_v1, g1v, b1vn, ss_v1, 1.f / N_NODES};
    FinArgs fe{st_e1, g1e, b1en, ss_e1, 1.f / N_EDGES};
    k_finstats<<<2, 128, 0, stream>>>(fv, fe);
  }

  k_ffn<<<391, 512, 0, stream>>>(v1b, ss_v1, img + 196608 /*W1v*/, b1vf,
                                 img + 262144 /*W2v*/, b2vf, st_v2, N_NODES);
  k_ffn<<<3907, 512, 0, stream>>>(e1b, ss_e1, img + 327680 /*W1e*/, b1ef,
                                  img + 393216 /*W2e*/, b2ef, st_e2, N_EDGES);

  NormP npv{st_v2, g2v, b2vn, 1.f / N_NODES};
  NormP npe{st_e2, g2e, b2en, 1.f / N_EDGES};
  k_norm2<<<4096, 256, 0, stream>>>((char*)out_v, (char*)out_e, npv, npe,
                                    (long long)N_NODES, (long long)N_EDGES);
}